// Round 17
// baseline (128.205 us; speedup 1.0000x reference)
//
#include <hip/hip_runtime.h>
#include <hip/hip_bf16.h>

typedef _Float16 f16;
typedef _Float16 f16x2 __attribute__((ext_vector_type(2)));
typedef _Float16 f16x4 __attribute__((ext_vector_type(4)));
typedef _Float16 f16x8 __attribute__((ext_vector_type(8)));
typedef __fp16 h16x2 __attribute__((ext_vector_type(2)));
typedef float f32x4 __attribute__((ext_vector_type(4)));

#define DIM 1024
#define SEQ 2048
#define NB 2
#define NH 16
#define DHEAD 64
#define KVB 64
#define QBLK 128
#define NT (SEQ / KVB)

// async global->LDS, 16B per lane. LDS dest = wave-uniform base (HW adds lane*16).
__device__ __forceinline__ void gl_lds16(const f16* g, f16* l) {
  __builtin_amdgcn_global_load_lds(
      (const __attribute__((address_space(1))) unsigned int*)(g),
      (__attribute__((address_space(3))) unsigned int*)(l), 16, 0, 0);
}

__device__ __forceinline__ f16x2 pkrtz(float a, float b) {
  h16x2 t = __builtin_amdgcn_cvt_pkrtz(a, b);
  return __builtin_bit_cast(f16x2, t);
}

// ---------------- fused: RMS-norm+cast (blocks 0..8191) | weight transpose (8192..12287) ----
__global__ __launch_bounds__(256) void fused_pre_kernel(
    const float* __restrict__ x, const float* __restrict__ ctx,
    const float* __restrict__ gamma,
    const float* __restrict__ Wq, const float* __restrict__ Wkv, const float* __restrict__ Wout,
    f16* __restrict__ xn, f16* __restrict__ cn,
    f16* __restrict__ WqT, f16* __restrict__ WkvT, f16* __restrict__ WoT)
{
  __shared__ float tile[32][33];
  int bx = blockIdx.x;
  if (bx < 2 * NB * SEQ) {
    int row = bx;
    const float* src; f16* dst;
    if (row < NB * SEQ) { src = x + (size_t)row * DIM;              dst = xn + (size_t)row * DIM; }
    else                { src = ctx + (size_t)(row - NB*SEQ) * DIM; dst = cn + (size_t)(row - NB*SEQ) * DIM; }
    int t = threadIdx.x;
    float4 v = ((const float4*)src)[t];
    float ss = v.x*v.x + v.y*v.y + v.z*v.z + v.w*v.w;
    #pragma unroll
    for (int m = 1; m < 64; m <<= 1) ss += __shfl_xor(ss, m, 64);
    if ((t & 63) == 0) tile[0][t >> 6] = ss;
    __syncthreads();
    float total = tile[0][0] + tile[0][1] + tile[0][2] + tile[0][3];
    float scale = 32.0f / fmaxf(sqrtf(total), 1e-12f);
    float4 gv = ((const float4*)gamma)[t];
    dst[4*t+0] = (f16)(v.x * scale * gv.x);
    dst[4*t+1] = (f16)(v.y * scale * gv.y);
    dst[4*t+2] = (f16)(v.z * scale * gv.z);
    dst[4*t+3] = (f16)(v.w * scale * gv.w);
  } else {
    int t2 = bx - 2 * NB * SEQ;
    int bxx = t2 & 127;
    int k0 = (t2 >> 7) * 32;
    const float* W; f16* Wt; int N, n0;
    if (bxx < 32)      { W = Wq;   Wt = WqT;  N = 1024; n0 = bxx * 32; }
    else if (bxx < 96) { W = Wkv;  Wt = WkvT; N = 2048; n0 = (bxx - 32) * 32; }
    else               { W = Wout; Wt = WoT;  N = 1024; n0 = (bxx - 96) * 32; }
    int tx = threadIdx.x & 31, ty = threadIdx.x >> 5;
    #pragma unroll
    for (int i = 0; i < 32; i += 8)
      tile[ty + i][tx] = W[(size_t)(k0 + ty + i) * N + n0 + tx];
    __syncthreads();
    #pragma unroll
    for (int i = 0; i < 32; i += 8)
      Wt[(size_t)(n0 + ty + i) * 1024 + k0 + tx] = (f16)tile[tx][ty + i];
  }
}

// ---------------- fused Q-proj + KV-proj GEMM: 1536 blocks, 128x64 tile, BK=64 dbuf ----
__global__ __launch_bounds__(256, 3) void gemm_qkv_kernel(
    const f16* __restrict__ xn, const f16* __restrict__ cn,
    const f16* __restrict__ WqT, const f16* __restrict__ WkvT,
    const float* __restrict__ scores,
    f16* __restrict__ qb, f16* __restrict__ kb, f16* __restrict__ vbT)
{
  __shared__ __align__(16) char L[49152];   // 2 bufs x (A 16KB + B 8KB)

  const int bid = blockIdx.x;
  const f16 *A, *Bt; int m0, n0, mode;
  if (bid < 512) { mode = 0; A = xn; Bt = WqT;  m0 = (bid & 31) * 128; n0 = (bid >> 5) * 64; }
  else { int id = bid - 512; mode = 1; A = cn; Bt = WkvT; m0 = (id & 31) * 128; n0 = (id >> 5) * 64; }

  const int tid = threadIdx.x, lane = tid & 63, w = tid >> 6;
  const int wm = w >> 1, wn = w & 1;
  const int g = lane >> 4, c = lane & 15;

  const int sj = lane >> 3;
  const int sl = (lane & 7) ^ sj;
  const f16* gA = A  + (size_t)(m0 + w*32 + sj) * 1024 + sl * 8;
  const f16* gB = Bt + (size_t)(n0 + w*16 + sj) * 1024 + sl * 8;
  const unsigned stA = w * 4096;
  const unsigned stB = 16384 + w * 2048;
  const unsigned swz = (c & 7) << 4;

  f32x4 acc[4][2] = {};

#define GSTAGE(k0v, buf) {                                                      \
    _Pragma("unroll")                                                           \
    for (int i2 = 0; i2 < 4; i2++)                                              \
      gl_lds16(gA + (size_t)(8*i2) * 1024 + (k0v), (f16*)(L + (buf) + stA + i2*1024)); \
    _Pragma("unroll")                                                           \
    for (int i2 = 0; i2 < 2; i2++)                                              \
      gl_lds16(gB + (size_t)(8*i2) * 1024 + (k0v), (f16*)(L + (buf) + stB + i2*1024)); }

  GSTAGE(0, 0)
  __syncthreads();

  for (int t = 0; t < 16; ++t) {
    const unsigned cur = (t & 1) ? 24576u : 0u;
    if (t + 1 < 16) GSTAGE((t + 1) * 64, cur ^ 24576u)
    #pragma unroll
    for (int kk = 0; kk < 2; kk++) {
      f16x8 af[4], bf[2];
      #pragma unroll
      for (int tm = 0; tm < 4; tm++)
        af[tm] = *(const f16x8*)(L + cur + (wm*64 + tm*16 + c)*128 + (((kk*4 + g) << 4) ^ swz));
      #pragma unroll
      for (int tn = 0; tn < 2; tn++)
        bf[tn] = *(const f16x8*)(L + cur + 16384 + (wn*32 + tn*16 + c)*128 + (((kk*4 + g) << 4) ^ swz));
      #pragma unroll
      for (int tm = 0; tm < 4; tm++)
        #pragma unroll
        for (int tn = 0; tn < 2; tn++)
          acc[tm][tn] = __builtin_amdgcn_mfma_f32_16x16x32_f16(af[tm], bf[tn], acc[tm][tn], 0, 0, 0);
    }
    __syncthreads();
  }
#undef GSTAGE

  #pragma unroll
  for (int tm = 0; tm < 4; tm++) {
    #pragma unroll
    for (int tn = 0; tn < 2; tn++) {
      int rg0 = m0 + wm*64 + tm*16 + g*4;
      int cg  = n0 + wn*32 + tn*16 + c;
      int b = rg0 >> 11, s0 = rg0 & 2047;
      if (mode == 0) {
        int h = cg >> 6, d = cg & 63;
        #pragma unroll
        for (int r = 0; r < 4; r++)
          qb[(((size_t)(b*NH + h))*SEQ + s0 + r)*DHEAD + d] =
              (f16)(acc[tm][tn][r] * 0.18033688011112043f);  // SCALE*log2(e)
      } else {
        int hh = (cg & 1023) >> 6, d = cg & 63;
        if (cg < 1024) {
          #pragma unroll
          for (int r = 0; r < 4; r++)
            kb[(((size_t)(b*NH + hh))*SEQ + s0 + r)*DHEAD + d] = (f16)acc[tm][tn][r];
        } else {
          float4 sc = *(const float4*)(scores + b*SEQ + s0);
          f16x4 pk;
          pk[0] = (f16)(acc[tm][tn][0] * sc.x);
          pk[1] = (f16)(acc[tm][tn][1] * sc.y);
          pk[2] = (f16)(acc[tm][tn][2] * sc.z);
          pk[3] = (f16)(acc[tm][tn][3] * sc.w);
          *(f16x4*)(vbT + (((size_t)(b*NH + hh))*DHEAD + d)*SEQ + s0) = pk;
        }
      }
    }
  }
}

// ---------------- out-proj GEMM: 128x64 tile, BK=64 dbuf, grid 512 ----------------
__global__ __launch_bounds__(256, 3) void gemm_out_kernel(
    const f16* __restrict__ A, const f16* __restrict__ Bt, float* __restrict__ o32)
{
  __shared__ __align__(16) char L[49152];

  const int m0 = blockIdx.x * 128, n0 = blockIdx.y * 64;
  const int tid = threadIdx.x, lane = tid & 63, w = tid >> 6;
  const int wm = w >> 1, wn = w & 1;
  const int g = lane >> 4, c = lane & 15;

  const int sj = lane >> 3;
  const int sl = (lane & 7) ^ sj;
  const f16* gA = A  + (size_t)(m0 + w*32 + sj) * 1024 + sl * 8;
  const f16* gB = Bt + (size_t)(n0 + w*16 + sj) * 1024 + sl * 8;
  const unsigned stA = w * 4096;
  const unsigned stB = 16384 + w * 2048;
  const unsigned swz = (c & 7) << 4;

  f32x4 acc[4][2] = {};

#define GSTAGE(k0v, buf) {                                                      \
    _Pragma("unroll")                                                           \
    for (int i2 = 0; i2 < 4; i2++)                                              \
      gl_lds16(gA + (size_t)(8*i2) * 1024 + (k0v), (f16*)(L + (buf) + stA + i2*1024)); \
    _Pragma("unroll")                                                           \
    for (int i2 = 0; i2 < 2; i2++)                                              \
      gl_lds16(gB + (size_t)(8*i2) * 1024 + (k0v), (f16*)(L + (buf) + stB + i2*1024)); }

  GSTAGE(0, 0)
  __syncthreads();

  for (int t = 0; t < 16; ++t) {
    const unsigned cur = (t & 1) ? 24576u : 0u;
    if (t + 1 < 16) GSTAGE((t + 1) * 64, cur ^ 24576u)
    #pragma unroll
    for (int kk = 0; kk < 2; kk++) {
      f16x8 af[4], bf[2];
      #pragma unroll
      for (int tm = 0; tm < 4; tm++)
        af[tm] = *(const f16x8*)(L + cur + (wm*64 + tm*16 + c)*128 + (((kk*4 + g) << 4) ^ swz));
      #pragma unroll
      for (int tn = 0; tn < 2; tn++)
        bf[tn] = *(const f16x8*)(L + cur + 16384 + (wn*32 + tn*16 + c)*128 + (((kk*4 + g) << 4) ^ swz));
      #pragma unroll
      for (int tm = 0; tm < 4; tm++)
        #pragma unroll
        for (int tn = 0; tn < 2; tn++)
          acc[tm][tn] = __builtin_amdgcn_mfma_f32_16x16x32_f16(af[tm], bf[tn], acc[tm][tn], 0, 0, 0);
    }
    __syncthreads();
  }
#undef GSTAGE

  #pragma unroll
  for (int tm = 0; tm < 4; tm++)
    #pragma unroll
    for (int tn = 0; tn < 2; tn++) {
      int rg0 = m0 + wm*64 + tm*16 + g*4;
      int cg  = n0 + wn*32 + tn*16 + c;
      #pragma unroll
      for (int r = 0; r < 4; r++)
        o32[(size_t)(rg0 + r) * 1024 + cg] = acc[tm][tn][r];
    }
}

// ---------------- flash attention: r16 structure + in-register P (shfl redistribution) ----
// S^T = K Q^T (per-lane softmax), O^T = V^T P^T. P never touches LDS in the loop:
// lane (g,c) holds P^T[kv=ct*16+4g+r][q=qs*16+c] as pkv[ct][qs]; PV B-frag for
// (kc,qs) is assembled from src lanes (g&1)*32+c and +16 via 8 shfl + 4 selects
// (register pair pkv[kc*2]/pkv[kc*2+1] chosen by target's g>>1 bit).
#define PT_OFF 32768

__global__ __launch_bounds__(256, 3) void attn_kernel(
    const f16* __restrict__ Q, const f16* __restrict__ K,
    const f16* __restrict__ Vt, f16* __restrict__ O)
{
  __shared__ __align__(16) char L[51200];

  const int bid = blockIdx.x;                        // 512 blocks
  const int xcd = bid & 7, i = bid >> 3;
  const int bh  = xcd*4 + (i >> 4);                  // 4 heads per XCD
  const int q0  = (i & 15) * QBLK;
  const int tid = threadIdx.x, lane = tid & 63, w = tid >> 6;
  const int g = lane >> 4, c = lane & 15;

  const f16* Qb  = Q  + (size_t)bh * SEQ * DHEAD;
  const f16* Kb  = K  + (size_t)bh * SEQ * DHEAD;
  const f16* Vbt = Vt + (size_t)bh * DHEAD * SEQ;    // [d][kv]

  f16x8 aq[2][2];
  #pragma unroll
  for (int qs = 0; qs < 2; qs++) {
    int qr = q0 + w*32 + qs*16 + c;
    aq[qs][0] = *(const f16x8*)(Qb + (size_t)qr * DHEAD + g*8);
    aq[qs][1] = *(const f16x8*)(Qb + (size_t)qr * DHEAD + 32 + g*8);
  }

  f32x4 oacc[2][4] = {};            // O^T: oacc[qs][dt][r] = O[q=qs*16+c][d=dt*16+4g+r]
  float mr[2] = {-1e30f, -1e30f};
  float lr[2] = {0.f, 0.f};

  const int sj = lane >> 3;                    // row within 1KB chunk (8 rows)
  const int sl = (lane & 7) ^ sj;              // pre-swizzled source chunk
  const f16* kgb0 = Kb  + (size_t)(w*16     + sj) * DHEAD + sl*8;
  const f16* kgb1 = Kb  + (size_t)(w*16 + 8 + sj) * DHEAD + sl*8;
  const f16* vgb0 = Vbt + (size_t)(w*16     + sj) * SEQ   + sl*8;
  const f16* vgb1 = Vbt + (size_t)(w*16 + 8 + sj) * SEQ   + sl*8;

  const unsigned ptb = PT_OFF + w*4608;            // epilogue bounce only
  const unsigned sw0 = ((g     ^ (c & 7)) << 4);   // kc=0 chunk swizzle
  const unsigned sw1 = (((4+g) ^ (c & 7)) << 4);   // kc=1

  f32x4 s[4][2];
  f16x4 pkv[4][2];
  const int psrc0 = ((g & 1) << 5) + c;            // P shfl source lane 0 (+16 for lane 1)
  const int psel  = (g >> 1) & 1;                  // register-pair select

  // assemble PV B-frag for (kc,qs) from in-register P
#define PSHUF(kc, qs, bp) {                                                        \
    int2 pa = __builtin_bit_cast(int2, pkv[(kc)*2][qs]);                           \
    int2 pb = __builtin_bit_cast(int2, pkv[(kc)*2 + 1][qs]);                       \
    int a0 = __shfl(pa.x, psrc0, 64),      a1 = __shfl(pa.y, psrc0, 64);           \
    int b0 = __shfl(pb.x, psrc0, 64),      b1 = __shfl(pb.y, psrc0, 64);           \
    int a2 = __shfl(pa.x, psrc0 + 16, 64), a3 = __shfl(pa.y, psrc0 + 16, 64);      \
    int b2 = __shfl(pb.x, psrc0 + 16, 64), b3 = __shfl(pb.y, psrc0 + 16, 64);      \
    int4 rres;                                                                     \
    rres.x = psel ? b0 : a0; rres.y = psel ? b1 : a1;                              \
    rres.z = psel ? b2 : a2; rres.w = psel ? b3 : a3;                              \
    bp = __builtin_bit_cast(f16x8, rres); }

#define STAGE(kv0v, slot) {                                                        \
    gl_lds16(kgb0 + (size_t)(kv0v)*DHEAD, (f16*)(L + (slot) + w*2048));            \
    gl_lds16(kgb1 + (size_t)(kv0v)*DHEAD, (f16*)(L + (slot) + w*2048 + 1024));     \
    gl_lds16(vgb0 + (kv0v),               (f16*)(L + (slot) + 8192 + w*2048));     \
    gl_lds16(vgb1 + (kv0v),               (f16*)(L + (slot) + 8192 + w*2048 + 1024)); }

#define QK_TILE(slot) {                                                            \
    _Pragma("unroll")                                                              \
    for (int ct = 0; ct < 4; ct++) {                                               \
      f16x8 k0 = *(const f16x8*)(L + (slot) + (ct*16 + c)*128 + sw0);              \
      f16x8 k1 = *(const f16x8*)(L + (slot) + (ct*16 + c)*128 + sw1);              \
      f32x4 z = {0.f, 0.f, 0.f, 0.f};                                              \
      s[ct][0] = __builtin_amdgcn_mfma_f32_16x16x32_f16(k0, aq[0][0], z, 0, 0, 0); \
      s[ct][0] = __builtin_amdgcn_mfma_f32_16x16x32_f16(k1, aq[0][1], s[ct][0], 0, 0, 0); \
      s[ct][1] = __builtin_amdgcn_mfma_f32_16x16x32_f16(k0, aq[1][0], z, 0, 0, 0); \
      s[ct][1] = __builtin_amdgcn_mfma_f32_16x16x32_f16(k1, aq[1][1], s[ct][1], 0, 0, 0); \
    } }

#define SOFTMAX_R() {                                                              \
    float mx0 = -1e30f, mx1 = -1e30f;                                              \
    _Pragma("unroll")                                                              \
    for (int ct = 0; ct < 4; ct++) {                                               \
      mx0 = fmaxf(mx0, fmaxf(fmaxf(s[ct][0][0], s[ct][0][1]), fmaxf(s[ct][0][2], s[ct][0][3]))); \
      mx1 = fmaxf(mx1, fmaxf(fmaxf(s[ct][1][0], s[ct][1][1]), fmaxf(s[ct][1][2], s[ct][1][3]))); \
    }                                                                              \
    mx0 = fmaxf(mx0, __shfl_xor(mx0, 16, 64)); mx0 = fmaxf(mx0, __shfl_xor(mx0, 32, 64)); \
    mx1 = fmaxf(mx1, __shfl_xor(mx1, 16, 64)); mx1 = fmaxf(mx1, __shfl_xor(mx1, 32, 64)); \
    if (!__all((mx0 <= mr[0] + 8.f) && (mx1 <= mr[1] + 8.f))) {                    \
      _Pragma("unroll")                                                            \
      for (int qs = 0; qs < 2; qs++) {                                             \
        float mxq = qs ? mx1 : mx0;                                                \
        float mn = fmaxf(mr[qs], mxq);                                             \
        float al = __builtin_amdgcn_exp2f(mr[qs] - mn);                            \
        mr[qs] = mn; lr[qs] *= al;                                                 \
        _Pragma("unroll")                                                          \
        for (int dt = 0; dt < 4; dt++)                                             \
          { oacc[qs][dt][0]*=al; oacc[qs][dt][1]*=al; oacc[qs][dt][2]*=al; oacc[qs][dt][3]*=al; } \
      }                                                                            \
    }                                                                              \
    _Pragma("unroll")                                                              \
    for (int qs = 0; qs < 2; qs++) {                                               \
      float rs = 0.f;                                                              \
      _Pragma("unroll")                                                            \
      for (int ct = 0; ct < 4; ct++) {                                             \
        float p0 = __builtin_amdgcn_exp2f(s[ct][qs][0] - mr[qs]);                  \
        float p1 = __builtin_amdgcn_exp2f(s[ct][qs][1] - mr[qs]);                  \
        float p2 = __builtin_amdgcn_exp2f(s[ct][qs][2] - mr[qs]);                  \
        float p3 = __builtin_amdgcn_exp2f(s[ct][qs][3] - mr[qs]);                  \
        rs += (p0 + p1) + (p2 + p3);                                               \
        f16x2 lo = pkrtz(p0, p1), hi = pkrtz(p2, p3);                              \
        pkv[ct][qs] = __builtin_shufflevector(lo, hi, 0, 1, 2, 3);                 \
      }                                                                            \
      rs += __shfl_xor(rs, 16, 64); rs += __shfl_xor(rs, 32, 64);                  \
      lr[qs] += rs;                                                                \
    } }

#define PV_TILE(slot) {                                                            \
    _Pragma("unroll")                                                              \
    for (int kc = 0; kc < 2; kc++) {                                               \
      f16x8 bp0, bp1;                                                              \
      PSHUF(kc, 0, bp0)                                                            \
      PSHUF(kc, 1, bp1)                                                            \
      unsigned swc = kc ? sw1 : sw0;                                               \
      _Pragma("unroll")                                                            \
      for (int dt = 0; dt < 4; dt++) {                                             \
        f16x8 vf = *(const f16x8*)(L + (slot) + 8192 + (dt*16 + c)*128 + swc);     \
        oacc[0][dt] = __builtin_amdgcn_mfma_f32_16x16x32_f16(vf, bp0, oacc[0][dt], 0, 0, 0); \
        oacc[1][dt] = __builtin_amdgcn_mfma_f32_16x16x32_f16(vf, bp1, oacc[1][dt], 0, 0, 0); \
      }                                                                            \
    } }

  STAGE(0, 0);
  __syncthreads();

  for (int t = 0; t < NT; ++t) {
    const unsigned cur = (t & 1) ? 16384u : 0u;
    const unsigned nxt = cur ^ 16384u;
    if (t + 1 < NT) STAGE((t + 1) * KVB, nxt);
    __builtin_amdgcn_s_setprio(1);
    QK_TILE(cur);
    __builtin_amdgcn_s_setprio(0);
    SOFTMAX_R();
    __builtin_amdgcn_s_setprio(1);
    PV_TILE(cur);
    __builtin_amdgcn_s_setprio(0);
    __syncthreads();
  }

  #pragma unroll
  for (int qs = 0; qs < 2; qs++) {
    float inv = 1.0f / lr[qs];
    #pragma unroll
    for (int dt = 0; dt < 4; dt++) {
      f16x4 ov;
      ov[0] = (f16)(oacc[qs][dt][0] * inv);
      ov[1] = (f16)(oacc[qs][dt][1] * inv);
      ov[2] = (f16)(oacc[qs][dt][2] * inv);
      ov[3] = (f16)(oacc[qs][dt][3] * inv);
      *(f16x4*)(L + ptb + (qs*16 + c)*144 + (dt*16 + 4*g)*2) = ov;
    }
  }
  {
    const int b = bh >> 4, h = bh & 15;
    #pragma unroll
    for (int p = 0; p < 2; p++) {
      int ql = p*16 + (lane >> 2), chq = lane & 3;
      const char* src = L + ptb + ql*144 + chq*32;
      float4 a0 = *(const float4*)src;
      float4 a1 = *(const float4*)(src + 16);
      f16* dst = O + ((size_t)(b*SEQ + q0 + w*32 + ql))*1024 + h*64 + chq*16;
      *(float4*)dst = a0;
      *(float4*)(dst + 8) = a1;
    }
  }
#undef STAGE
#undef QK_TILE
#undef SOFTMAX_R
#undef PV_TILE
#undef PSHUF
}

extern "C" void kernel_launch(void* const* d_in, const int* in_sizes, int n_in,
                              void* d_out, int out_size, void* d_ws, size_t ws_size,
                              hipStream_t stream)
{
  const float* x      = (const float*)d_in[0];
  const float* ctx    = (const float*)d_in[1];
  const float* scores = (const float*)d_in[2];
  const float* gamma  = (const float*)d_in[4];
  const float* Wq     = (const float*)d_in[5];
  const float* Wkv    = (const float*)d_in[6];
  const float* Wout   = (const float*)d_in[7];
  float* out = (float*)d_out;

  char* ws = (char*)d_ws;
  const size_t MB = 1024 * 1024;
  f16* xn   = (f16*)(ws);
  f16* cn   = (f16*)(ws + 8*MB);
  f16* WqT  = (f16*)(ws + 16*MB);
  f16* WkvT = (f16*)(ws + 18*MB);
  f16* WoT  = (f16*)(ws + 22*MB);
  f16* qb   = (f16*)(ws + 24*MB);
  f16* kb   = (f16*)(ws + 32*MB);
  f16* vbT  = (f16*)(ws + 40*MB);   // [b*h][d][kv]
  f16* ao   = xn;

  fused_pre_kernel<<<dim3(2*NB*SEQ + 4096), 256, 0, stream>>>(
      x, ctx, gamma, Wq, Wkv, Wout, xn, cn, WqT, WkvT, WoT);
  gemm_qkv_kernel<<<dim3(1536), 256, 0, stream>>>(xn, cn, WqT, WkvT, scores, qb, kb, vbT);
  attn_kernel<<<dim3(512), 256, 0, stream>>>(qb, kb, vbT, ao);
  gemm_out_kernel<<<dim3(32, 16), 256, 0, stream>>>(ao, WoT, out);
}

// Round 18
// 118.976 us; speedup vs baseline: 1.0776x; 1.0776x over previous
//
#include <hip/hip_runtime.h>
#include <hip/hip_bf16.h>

typedef _Float16 f16;
typedef _Float16 f16x2 __attribute__((ext_vector_type(2)));
typedef _Float16 f16x4 __attribute__((ext_vector_type(4)));
typedef _Float16 f16x8 __attribute__((ext_vector_type(8)));
typedef __fp16 h16x2 __attribute__((ext_vector_type(2)));
typedef float f32x4 __attribute__((ext_vector_type(4)));

#define DIM 1024
#define SEQ 2048
#define NB 2
#define NH 16
#define DHEAD 64
#define KVB 64
#define QBLK 128
#define NT (SEQ / KVB)

// async global->LDS, 16B per lane. LDS dest = wave-uniform base (HW adds lane*16).
__device__ __forceinline__ void gl_lds16(const f16* g, f16* l) {
  __builtin_amdgcn_global_load_lds(
      (const __attribute__((address_space(1))) unsigned int*)(g),
      (__attribute__((address_space(3))) unsigned int*)(l), 16, 0, 0);
}

__device__ __forceinline__ f16x2 pkrtz(float a, float b) {
  h16x2 t = __builtin_amdgcn_cvt_pkrtz(a, b);
  return __builtin_bit_cast(f16x2, t);
}

// ---------------- fused: RMS-norm+cast (blocks 0..8191) | weight transpose (8192..12287) ----
__global__ __launch_bounds__(256) void fused_pre_kernel(
    const float* __restrict__ x, const float* __restrict__ ctx,
    const float* __restrict__ gamma,
    const float* __restrict__ Wq, const float* __restrict__ Wkv, const float* __restrict__ Wout,
    f16* __restrict__ xn, f16* __restrict__ cn,
    f16* __restrict__ WqT, f16* __restrict__ WkvT, f16* __restrict__ WoT)
{
  __shared__ float tile[32][33];
  int bx = blockIdx.x;
  if (bx < 2 * NB * SEQ) {
    int row = bx;
    const float* src; f16* dst;
    if (row < NB * SEQ) { src = x + (size_t)row * DIM;              dst = xn + (size_t)row * DIM; }
    else                { src = ctx + (size_t)(row - NB*SEQ) * DIM; dst = cn + (size_t)(row - NB*SEQ) * DIM; }
    int t = threadIdx.x;
    float4 v = ((const float4*)src)[t];
    float ss = v.x*v.x + v.y*v.y + v.z*v.z + v.w*v.w;
    #pragma unroll
    for (int m = 1; m < 64; m <<= 1) ss += __shfl_xor(ss, m, 64);
    if ((t & 63) == 0) tile[0][t >> 6] = ss;
    __syncthreads();
    float total = tile[0][0] + tile[0][1] + tile[0][2] + tile[0][3];
    float scale = 32.0f / fmaxf(sqrtf(total), 1e-12f);
    float4 gv = ((const float4*)gamma)[t];
    dst[4*t+0] = (f16)(v.x * scale * gv.x);
    dst[4*t+1] = (f16)(v.y * scale * gv.y);
    dst[4*t+2] = (f16)(v.z * scale * gv.z);
    dst[4*t+3] = (f16)(v.w * scale * gv.w);
  } else {
    int t2 = bx - 2 * NB * SEQ;
    int bxx = t2 & 127;
    int k0 = (t2 >> 7) * 32;
    const float* W; f16* Wt; int N, n0;
    if (bxx < 32)      { W = Wq;   Wt = WqT;  N = 1024; n0 = bxx * 32; }
    else if (bxx < 96) { W = Wkv;  Wt = WkvT; N = 2048; n0 = (bxx - 32) * 32; }
    else               { W = Wout; Wt = WoT;  N = 1024; n0 = (bxx - 96) * 32; }
    int tx = threadIdx.x & 31, ty = threadIdx.x >> 5;
    #pragma unroll
    for (int i = 0; i < 32; i += 8)
      tile[ty + i][tx] = W[(size_t)(k0 + ty + i) * N + n0 + tx];
    __syncthreads();
    #pragma unroll
    for (int i = 0; i < 32; i += 8)
      Wt[(size_t)(n0 + ty + i) * 1024 + k0 + tx] = (f16)tile[tx][ty + i];
  }
}

// ---------------- fused Q-proj + KV-proj GEMM: 1536 blocks, 128x64 tile, BK=64 dbuf ----
__global__ __launch_bounds__(256, 3) void gemm_qkv_kernel(
    const f16* __restrict__ xn, const f16* __restrict__ cn,
    const f16* __restrict__ WqT, const f16* __restrict__ WkvT,
    const float* __restrict__ scores,
    f16* __restrict__ qb, f16* __restrict__ kb, f16* __restrict__ vbT)
{
  __shared__ __align__(16) char L[49152];   // 2 bufs x (A 16KB + B 8KB)

  const int bid = blockIdx.x;
  const f16 *A, *Bt; int m0, n0, mode;
  if (bid < 512) { mode = 0; A = xn; Bt = WqT;  m0 = (bid & 31) * 128; n0 = (bid >> 5) * 64; }
  else { int id = bid - 512; mode = 1; A = cn; Bt = WkvT; m0 = (id & 31) * 128; n0 = (id >> 5) * 64; }

  const int tid = threadIdx.x, lane = tid & 63, w = tid >> 6;
  const int wm = w >> 1, wn = w & 1;
  const int g = lane >> 4, c = lane & 15;

  const int sj = lane >> 3;
  const int sl = (lane & 7) ^ sj;
  const f16* gA = A  + (size_t)(m0 + w*32 + sj) * 1024 + sl * 8;
  const f16* gB = Bt + (size_t)(n0 + w*16 + sj) * 1024 + sl * 8;
  const unsigned stA = w * 4096;
  const unsigned stB = 16384 + w * 2048;
  const unsigned swz = (c & 7) << 4;

  f32x4 acc[4][2] = {};

#define GSTAGE(k0v, buf) {                                                      \
    _Pragma("unroll")                                                           \
    for (int i2 = 0; i2 < 4; i2++)                                              \
      gl_lds16(gA + (size_t)(8*i2) * 1024 + (k0v), (f16*)(L + (buf) + stA + i2*1024)); \
    _Pragma("unroll")                                                           \
    for (int i2 = 0; i2 < 2; i2++)                                              \
      gl_lds16(gB + (size_t)(8*i2) * 1024 + (k0v), (f16*)(L + (buf) + stB + i2*1024)); }

  GSTAGE(0, 0)
  __syncthreads();

  for (int t = 0; t < 16; ++t) {
    const unsigned cur = (t & 1) ? 24576u : 0u;
    if (t + 1 < 16) GSTAGE((t + 1) * 64, cur ^ 24576u)
    #pragma unroll
    for (int kk = 0; kk < 2; kk++) {
      f16x8 af[4], bf[2];
      #pragma unroll
      for (int tm = 0; tm < 4; tm++)
        af[tm] = *(const f16x8*)(L + cur + (wm*64 + tm*16 + c)*128 + (((kk*4 + g) << 4) ^ swz));
      #pragma unroll
      for (int tn = 0; tn < 2; tn++)
        bf[tn] = *(const f16x8*)(L + cur + 16384 + (wn*32 + tn*16 + c)*128 + (((kk*4 + g) << 4) ^ swz));
      #pragma unroll
      for (int tm = 0; tm < 4; tm++)
        #pragma unroll
        for (int tn = 0; tn < 2; tn++)
          acc[tm][tn] = __builtin_amdgcn_mfma_f32_16x16x32_f16(af[tm], bf[tn], acc[tm][tn], 0, 0, 0);
    }
    __syncthreads();
  }
#undef GSTAGE

  #pragma unroll
  for (int tm = 0; tm < 4; tm++) {
    #pragma unroll
    for (int tn = 0; tn < 2; tn++) {
      int rg0 = m0 + wm*64 + tm*16 + g*4;
      int cg  = n0 + wn*32 + tn*16 + c;
      int b = rg0 >> 11, s0 = rg0 & 2047;
      if (mode == 0) {
        int h = cg >> 6, d = cg & 63;
        #pragma unroll
        for (int r = 0; r < 4; r++)
          qb[(((size_t)(b*NH + h))*SEQ + s0 + r)*DHEAD + d] =
              (f16)(acc[tm][tn][r] * 0.18033688011112043f);  // SCALE*log2(e)
      } else {
        int hh = (cg & 1023) >> 6, d = cg & 63;
        if (cg < 1024) {
          #pragma unroll
          for (int r = 0; r < 4; r++)
            kb[(((size_t)(b*NH + hh))*SEQ + s0 + r)*DHEAD + d] = (f16)acc[tm][tn][r];
        } else {
          float4 sc = *(const float4*)(scores + b*SEQ + s0);
          f16x4 pk;
          pk[0] = (f16)(acc[tm][tn][0] * sc.x);
          pk[1] = (f16)(acc[tm][tn][1] * sc.y);
          pk[2] = (f16)(acc[tm][tn][2] * sc.z);
          pk[3] = (f16)(acc[tm][tn][3] * sc.w);
          *(f16x4*)(vbT + (((size_t)(b*NH + hh))*DHEAD + d)*SEQ + s0) = pk;
        }
      }
    }
  }
}

// ---------------- out-proj GEMM: 128x64 tile, BK=64 dbuf, grid 512 ----------------
__global__ __launch_bounds__(256, 3) void gemm_out_kernel(
    const f16* __restrict__ A, const f16* __restrict__ Bt, float* __restrict__ o32)
{
  __shared__ __align__(16) char L[49152];

  const int m0 = blockIdx.x * 128, n0 = blockIdx.y * 64;
  const int tid = threadIdx.x, lane = tid & 63, w = tid >> 6;
  const int wm = w >> 1, wn = w & 1;
  const int g = lane >> 4, c = lane & 15;

  const int sj = lane >> 3;
  const int sl = (lane & 7) ^ sj;
  const f16* gA = A  + (size_t)(m0 + w*32 + sj) * 1024 + sl * 8;
  const f16* gB = Bt + (size_t)(n0 + w*16 + sj) * 1024 + sl * 8;
  const unsigned stA = w * 4096;
  const unsigned stB = 16384 + w * 2048;
  const unsigned swz = (c & 7) << 4;

  f32x4 acc[4][2] = {};

#define GSTAGE(k0v, buf) {                                                      \
    _Pragma("unroll")                                                           \
    for (int i2 = 0; i2 < 4; i2++)                                              \
      gl_lds16(gA + (size_t)(8*i2) * 1024 + (k0v), (f16*)(L + (buf) + stA + i2*1024)); \
    _Pragma("unroll")                                                           \
    for (int i2 = 0; i2 < 2; i2++)                                              \
      gl_lds16(gB + (size_t)(8*i2) * 1024 + (k0v), (f16*)(L + (buf) + stB + i2*1024)); }

  GSTAGE(0, 0)
  __syncthreads();

  for (int t = 0; t < 16; ++t) {
    const unsigned cur = (t & 1) ? 24576u : 0u;
    if (t + 1 < 16) GSTAGE((t + 1) * 64, cur ^ 24576u)
    #pragma unroll
    for (int kk = 0; kk < 2; kk++) {
      f16x8 af[4], bf[2];
      #pragma unroll
      for (int tm = 0; tm < 4; tm++)
        af[tm] = *(const f16x8*)(L + cur + (wm*64 + tm*16 + c)*128 + (((kk*4 + g) << 4) ^ swz));
      #pragma unroll
      for (int tn = 0; tn < 2; tn++)
        bf[tn] = *(const f16x8*)(L + cur + 16384 + (wn*32 + tn*16 + c)*128 + (((kk*4 + g) << 4) ^ swz));
      #pragma unroll
      for (int tm = 0; tm < 4; tm++)
        #pragma unroll
        for (int tn = 0; tn < 2; tn++)
          acc[tm][tn] = __builtin_amdgcn_mfma_f32_16x16x32_f16(af[tm], bf[tn], acc[tm][tn], 0, 0, 0);
    }
    __syncthreads();
  }
#undef GSTAGE

  #pragma unroll
  for (int tm = 0; tm < 4; tm++)
    #pragma unroll
    for (int tn = 0; tn < 2; tn++) {
      int rg0 = m0 + wm*64 + tm*16 + g*4;
      int cg  = n0 + wn*32 + tn*16 + c;
      #pragma unroll
      for (int r = 0; r < 4; r++)
        o32[(size_t)(rg0 + r) * 1024 + cg] = acc[tm][tn][r];
    }
}

// ---------------- flash attention: r16 structure + V-frag hoist ahead of softmax ----
#define PT_OFF 32768

__global__ __launch_bounds__(256, 3) void attn_kernel(
    const f16* __restrict__ Q, const f16* __restrict__ K,
    const f16* __restrict__ Vt, f16* __restrict__ O)
{
  __shared__ __align__(16) char L[51200];

  const int bid = blockIdx.x;                        // 512 blocks
  const int xcd = bid & 7, i = bid >> 3;
  const int bh  = xcd*4 + (i >> 4);                  // 4 heads per XCD
  const int q0  = (i & 15) * QBLK;
  const int tid = threadIdx.x, lane = tid & 63, w = tid >> 6;
  const int g = lane >> 4, c = lane & 15;

  const f16* Qb  = Q  + (size_t)bh * SEQ * DHEAD;
  const f16* Kb  = K  + (size_t)bh * SEQ * DHEAD;
  const f16* Vbt = Vt + (size_t)bh * DHEAD * SEQ;    // [d][kv]

  f16x8 aq[2][2];
  #pragma unroll
  for (int qs = 0; qs < 2; qs++) {
    int qr = q0 + w*32 + qs*16 + c;
    aq[qs][0] = *(const f16x8*)(Qb + (size_t)qr * DHEAD + g*8);
    aq[qs][1] = *(const f16x8*)(Qb + (size_t)qr * DHEAD + 32 + g*8);
  }

  f32x4 oacc[2][4] = {};            // O^T: oacc[qs][dt][r] = O[q=qs*16+c][d=dt*16+4g+r]
  float mr[2] = {-1e30f, -1e30f};
  float lr[2] = {0.f, 0.f};

  const int sj = lane >> 3;                    // row within 1KB chunk (8 rows)
  const int sl = (lane & 7) ^ sj;              // pre-swizzled source chunk
  const f16* kgb0 = Kb  + (size_t)(w*16     + sj) * DHEAD + sl*8;
  const f16* kgb1 = Kb  + (size_t)(w*16 + 8 + sj) * DHEAD + sl*8;
  const f16* vgb0 = Vbt + (size_t)(w*16     + sj) * SEQ   + sl*8;
  const f16* vgb1 = Vbt + (size_t)(w*16 + 8 + sj) * SEQ   + sl*8;

  const unsigned ptb = PT_OFF + w*4608;
  const unsigned sw0 = ((g     ^ (c & 7)) << 4);   // kc=0 chunk swizzle
  const unsigned sw1 = (((4+g) ^ (c & 7)) << 4);   // kc=1

  f32x4 s[4][2];
  f16x8 vfr[2][4];                  // hoisted V fragments

#define STAGE(kv0v, slot) {                                                        \
    gl_lds16(kgb0 + (size_t)(kv0v)*DHEAD, (f16*)(L + (slot) + w*2048));            \
    gl_lds16(kgb1 + (size_t)(kv0v)*DHEAD, (f16*)(L + (slot) + w*2048 + 1024));     \
    gl_lds16(vgb0 + (kv0v),               (f16*)(L + (slot) + 8192 + w*2048));     \
    gl_lds16(vgb1 + (kv0v),               (f16*)(L + (slot) + 8192 + w*2048 + 1024)); }

#define QK_TILE(slot) {                                                            \
    _Pragma("unroll")                                                              \
    for (int ct = 0; ct < 4; ct++) {                                               \
      f16x8 k0 = *(const f16x8*)(L + (slot) + (ct*16 + c)*128 + sw0);              \
      f16x8 k1 = *(const f16x8*)(L + (slot) + (ct*16 + c)*128 + sw1);              \
      f32x4 z = {0.f, 0.f, 0.f, 0.f};                                              \
      s[ct][0] = __builtin_amdgcn_mfma_f32_16x16x32_f16(k0, aq[0][0], z, 0, 0, 0); \
      s[ct][0] = __builtin_amdgcn_mfma_f32_16x16x32_f16(k1, aq[0][1], s[ct][0], 0, 0, 0); \
      s[ct][1] = __builtin_amdgcn_mfma_f32_16x16x32_f16(k0, aq[1][0], z, 0, 0, 0); \
      s[ct][1] = __builtin_amdgcn_mfma_f32_16x16x32_f16(k1, aq[1][1], s[ct][1], 0, 0, 0); \
    } }

#define VLOAD(slot) {                                                              \
    _Pragma("unroll")                                                              \
    for (int kc = 0; kc < 2; kc++) {                                               \
      unsigned swc = kc ? sw1 : sw0;                                               \
      _Pragma("unroll")                                                            \
      for (int dt = 0; dt < 4; dt++)                                               \
        vfr[kc][dt] = *(const f16x8*)(L + (slot) + 8192 + (dt*16 + c)*128 + swc);  \
    } }

#define SOFTMAX_PW() {                                                            \
    float mx0 = -1e30f, mx1 = -1e30f;                                              \
    _Pragma("unroll")                                                              \
    for (int ct = 0; ct < 4; ct++) {                                               \
      mx0 = fmaxf(mx0, fmaxf(fmaxf(s[ct][0][0], s[ct][0][1]), fmaxf(s[ct][0][2], s[ct][0][3]))); \
      mx1 = fmaxf(mx1, fmaxf(fmaxf(s[ct][1][0], s[ct][1][1]), fmaxf(s[ct][1][2], s[ct][1][3]))); \
    }                                                                              \
    mx0 = fmaxf(mx0, __shfl_xor(mx0, 16, 64)); mx0 = fmaxf(mx0, __shfl_xor(mx0, 32, 64)); \
    mx1 = fmaxf(mx1, __shfl_xor(mx1, 16, 64)); mx1 = fmaxf(mx1, __shfl_xor(mx1, 32, 64)); \
    if (!__all((mx0 <= mr[0] + 8.f) && (mx1 <= mr[1] + 8.f))) {                    \
      _Pragma("unroll")                                                            \
      for (int qs = 0; qs < 2; qs++) {                                             \
        float mxq = qs ? mx1 : mx0;                                                \
        float mn = fmaxf(mr[qs], mxq);                                             \
        float al = __builtin_amdgcn_exp2f(mr[qs] - mn);                            \
        mr[qs] = mn; lr[qs] *= al;                                                 \
        _Pragma("unroll")                                                          \
        for (int dt = 0; dt < 4; dt++)                                             \
          { oacc[qs][dt][0]*=al; oacc[qs][dt][1]*=al; oacc[qs][dt][2]*=al; oacc[qs][dt][3]*=al; } \
      }                                                                            \
    }                                                                              \
    _Pragma("unroll")                                                              \
    for (int qs = 0; qs < 2; qs++) {                                               \
      float rs = 0.f;                                                              \
      _Pragma("unroll")                                                            \
      for (int ct = 0; ct < 4; ct++) {                                             \
        float p0 = __builtin_amdgcn_exp2f(s[ct][qs][0] - mr[qs]);                  \
        float p1 = __builtin_amdgcn_exp2f(s[ct][qs][1] - mr[qs]);                  \
        float p2 = __builtin_amdgcn_exp2f(s[ct][qs][2] - mr[qs]);                  \
        float p3 = __builtin_amdgcn_exp2f(s[ct][qs][3] - mr[qs]);                  \
        rs += (p0 + p1) + (p2 + p3);                                               \
        f16x2 lo = pkrtz(p0, p1), hi = pkrtz(p2, p3);                              \
        f16x4 pkv = __builtin_shufflevector(lo, hi, 0, 1, 2, 3);                   \
        *(f16x4*)(L + ptb + (qs*16 + c)*144 + ct*32 + g*8) = pkv;                  \
      }                                                                            \
      rs += __shfl_xor(rs, 16, 64); rs += __shfl_xor(rs, 32, 64);                  \
      lr[qs] += rs;                                                                \
    } }

#define PV_TILE() {                                                                \
    _Pragma("unroll")                                                              \
    for (int kc = 0; kc < 2; kc++) {                                               \
      f16x8 bp0 = *(const f16x8*)(L + ptb + c*144        + kc*64 + g*16);          \
      f16x8 bp1 = *(const f16x8*)(L + ptb + (16 + c)*144 + kc*64 + g*16);          \
      _Pragma("unroll")                                                            \
      for (int dt = 0; dt < 4; dt++) {                                             \
        oacc[0][dt] = __builtin_amdgcn_mfma_f32_16x16x32_f16(vfr[kc][dt], bp0, oacc[0][dt], 0, 0, 0); \
        oacc[1][dt] = __builtin_amdgcn_mfma_f32_16x16x32_f16(vfr[kc][dt], bp1, oacc[1][dt], 0, 0, 0); \
      }                                                                            \
    } }

  STAGE(0, 0);
  __syncthreads();

  for (int t = 0; t < NT; ++t) {
    const unsigned cur = (t & 1) ? 16384u : 0u;
    const unsigned nxt = cur ^ 16384u;
    if (t + 1 < NT) STAGE((t + 1) * KVB, nxt);
    __builtin_amdgcn_s_setprio(1);
    QK_TILE(cur);
    __builtin_amdgcn_s_setprio(0);
    VLOAD(cur);
    SOFTMAX_PW();
    __builtin_amdgcn_s_setprio(1);
    PV_TILE();
    __builtin_amdgcn_s_setprio(0);
    __syncthreads();
  }

  #pragma unroll
  for (int qs = 0; qs < 2; qs++) {
    float inv = 1.0f / lr[qs];
    #pragma unroll
    for (int dt = 0; dt < 4; dt++) {
      f16x4 ov;
      ov[0] = (f16)(oacc[qs][dt][0] * inv);
      ov[1] = (f16)(oacc[qs][dt][1] * inv);
      ov[2] = (f16)(oacc[qs][dt][2] * inv);
      ov[3] = (f16)(oacc[qs][dt][3] * inv);
      *(f16x4*)(L + ptb + (qs*16 + c)*144 + (dt*16 + 4*g)*2) = ov;
    }
  }
  {
    const int b = bh >> 4, h = bh & 15;
    #pragma unroll
    for (int p = 0; p < 2; p++) {
      int ql = p*16 + (lane >> 2), chq = lane & 3;
      const char* src = L + ptb + ql*144 + chq*32;
      float4 a0 = *(const float4*)src;
      float4 a1 = *(const float4*)(src + 16);
      f16* dst = O + ((size_t)(b*SEQ + q0 + w*32 + ql))*1024 + h*64 + chq*16;
      *(float4*)dst = a0;
      *(float4*)(dst + 8) = a1;
    }
  }
#undef STAGE
#undef QK_TILE
#undef VLOAD
#undef SOFTMAX_PW
#undef PV_TILE
}

extern "C" void kernel_launch(void* const* d_in, const int* in_sizes, int n_in,
                              void* d_out, int out_size, void* d_ws, size_t ws_size,
                              hipStream_t stream)
{
  const float* x      = (const float*)d_in[0];
  const float* ctx    = (const float*)d_in[1];
  const float* scores = (const float*)d_in[2];
  const float* gamma  = (const float*)d_in[4];
  const float* Wq     = (const float*)d_in[5];
  const float* Wkv    = (const float*)d_in[6];
  const float* Wout   = (const float*)d_in[7];
  float* out = (float*)d_out;

  char* ws = (char*)d_ws;
  const size_t MB = 1024 * 1024;
  f16* xn   = (f16*)(ws);
  f16* cn   = (f16*)(ws + 8*MB);
  f16* WqT  = (f16*)(ws + 16*MB);
  f16* WkvT = (f16*)(ws + 18*MB);
  f16* WoT  = (f16*)(ws + 22*MB);
  f16* qb   = (f16*)(ws + 24*MB);
  f16* kb   = (f16*)(ws + 32*MB);
  f16* vbT  = (f16*)(ws + 40*MB);   // [b*h][d][kv]
  f16* ao   = xn;

  fused_pre_kernel<<<dim3(2*NB*SEQ + 4096), 256, 0, stream>>>(
      x, ctx, gamma, Wq, Wkv, Wout, xn, cn, WqT, WkvT, WoT);
  gemm_qkv_kernel<<<dim3(1536), 256, 0, stream>>>(xn, cn, WqT, WkvT, scores, qb, kb, vbT);
  attn_kernel<<<dim3(512), 256, 0, stream>>>(qb, kb, vbT, ao);
  gemm_out_kernel<<<dim3(32, 16), 256, 0, stream>>>(ao, WoT, out);
}